// Round 7
// baseline (42344.421 us; speedup 1.0000x reference)
//
#include <hip/hip_runtime.h>
#include <hip/hip_bf16.h>
#include <cstddef>
#include <cstdint>

// ---------------------------------------------------------------------------
// RecurrentEncoderDecoder (B=128, T=512, H=512, HOR=64, M=1, Q=5, DFF=7)
// Round 7: round-6 persistent kernel with ALL sync ops dropped from SYSTEM
// scope to AGENT scope. Round-6 PMC showed 97% idle + 618 MB WRITE_SIZE:
// system-scope release flushed dirty L2 through L3 to HBM every barrier
// (~30 us/step). Agent release (buffer_wbl2 sc1) stops at the shared
// memory-side L3 (~1 us); agent relaxed loads (sc1) read L3-fresh.
// No acquire-invalidate anywhere -> weights stay L2-resident across steps.
// Everything else identical to the passing round-6 kernel.
// ---------------------------------------------------------------------------

typedef __attribute__((ext_vector_type(8))) short short8;
typedef __attribute__((ext_vector_type(4))) float f32x4;

__device__ __forceinline__ float sigm_(float x){ return 1.0f/(1.0f+__expf(-x)); }

__device__ __forceinline__ short bf16b(float x){
  __hip_bfloat16 h = __float2bfloat16(x);
  union { __hip_bfloat16 h; short s; } u; u.h = h; return u.s;
}

// 16B load, agent-scope relaxed (sc1: bypass local L2, served L3-fresh).
__device__ __forceinline__ short8 ld_agc8(const short* p){
  union { unsigned long long u[2]; short8 s; } cv;
  cv.u[0] = __hip_atomic_load((const unsigned long long*)p,     __ATOMIC_RELAXED, __HIP_MEMORY_SCOPE_AGENT);
  cv.u[1] = __hip_atomic_load(((const unsigned long long*)p)+1, __ATOMIC_RELAXED, __HIP_MEMORY_SCOPE_AGENT);
  return cv.s;
}
__device__ __forceinline__ float ld_agcf(const float* p){
  unsigned u = __hip_atomic_load((const unsigned*)p, __ATOMIC_RELAXED, __HIP_MEMORY_SCOPE_AGENT);
  union { unsigned u; float f; } c; c.u = u; return c.f;
}

// One B-segment of the gate GEMM. Ap already includes row*KT + q*8.
template<int KN, bool SYS>
__device__ __forceinline__ void gseg(const short* __restrict__ Ap,
                                     const short* __restrict__ S, int ld,
                                     int colr, int q, int a_k32_off,
                                     f32x4 (&acc)[4])
{
#pragma unroll 4
  for (int k32 = 0; k32 < KN; ++k32) {
    short8 a = *(const short8*)(Ap + (size_t)(a_k32_off + k32) * 32);
#pragma unroll
    for (int bn = 0; bn < 4; ++bn) {
      const short* bp = S + (size_t)(colr + bn * 16) * ld + k32 * 32 + q * 8;
      short8 b;
      if constexpr (SYS) b = ld_agc8(bp); else b = *(const short8*)bp;
      acc[bn] = __builtin_amdgcn_mfma_f32_16x16x32_bf16(a, b, acc[bn], 0, 0, 0);
    }
  }
}

// Tree grid barrier, agent scope. base points at [seq][16] u32 slots:
// leaves 0..nleaf-1 (16 arrivals each), root at slot 15.
// Agent release-add: vmcnt drain + L2->L3 writeback. Agent relaxed poll.
__device__ __forceinline__ void gbar(unsigned* base, int seq, int gbid, int nleaf)
{
  __syncthreads();
  if (threadIdx.x == 0) {
    unsigned* bb = base + (size_t)seq * 16;
    unsigned prev = __hip_atomic_fetch_add(bb + (gbid >> 4), 1u, __ATOMIC_RELEASE, __HIP_MEMORY_SCOPE_AGENT);
    if (prev == 15u)
      __hip_atomic_fetch_add(bb + 15, 1u, __ATOMIC_RELEASE, __HIP_MEMORY_SCOPE_AGENT);
    while (__hip_atomic_load(bb + 15, __ATOMIC_RELAXED, __HIP_MEMORY_SCOPE_AGENT) < (unsigned)nleaf)
      __builtin_amdgcn_s_sleep(1);
  }
  __syncthreads();
}

struct PK {
  const short *AL0, *AL1, *AD0, *AD1;   // packed bf16 weights
  const float *bpk;                      // packed biases [6][2048]
  short *ys1T;        // [512][128][1024] bf16 (L0 h record, fwd k<512 / bwd k>=512)
  short *xpT;         // [512][128][128] bf16, x padded
  short *h1T;         // [par2*dir2][128][512] bf16
  short *hdecT;       // [par2*lay2][128][512] bf16
  short *xdecTb;      // [128][128] bf16
  float *hfin0, *hfin1, *cfin0, *cfin1;  // [2][512][128] f32
  float *cdec;        // [2][512][128]
  float *hdecF;       // [512][128]
  const float *wbidi, *bbidi, *wout, *bout, *fut;
  float *out;
  unsigned *barF, *barB, *barFull, *barD;
};

__global__ __launch_bounds__(256) void k_perst(PK P)
{
  __shared__ float red[4][64];
  const int bid  = blockIdx.x;
  const int tid  = threadIdx.x;
  const int lane = tid & 63;
  const int w    = tid >> 6;
  const int r    = lane & 15, q = lane >> 4;
  const int dir  = bid >> 6;
  const int task = (bid & 63) * 4 + w;
  const int rt   = task >> 1, ct = task & 1;
  const int colbase = ct * 64;
  const int colr = colbase + r;
  const int rowr = rt * 16 + r;
  const int hg   = rt * 4 + q;          // global h row this lane owns
  const int prow4 = rt * 16 + q * 4;    // packed-row base for bias float4
  unsigned* barMy = dir ? P.barB : P.barF;

  // ================= encoder layer 0 (512 steps) =================
  {
    const short* A = P.AL0 + (size_t)dir * 2048 * 640;
    const float4 bv = *(const float4*)(P.bpk + dir * 2048 + prow4);
    const short* Ap = A + (size_t)rowr * 640 + q * 8;
    float c[4] = {0.f, 0.f, 0.f, 0.f};
    for (int s = 0; s < 512; ++s) {
      int t  = dir ? 511 - s : s;
      int tp = dir ? 512 - s : s - 1;     // prev-h time slab (unique addr/step)
      f32x4 acc[4];
#pragma unroll
      for (int bn = 0; bn < 4; ++bn) acc[bn] = (f32x4){0.f,0.f,0.f,0.f};
      if (s > 0)
        gseg<16, false>(Ap, P.ys1T + (size_t)tp * 131072 + dir * 512, 1024, colr, q, 0, acc);
      gseg<4, false>(Ap, P.xpT + (size_t)t * 16384, 128, colr, q, 16, acc);
#pragma unroll
      for (int bn = 0; bn < 4; ++bn) {
        int col = colbase + bn * 16 + r;
        float gi = acc[bn][0]+bv.x, gf = acc[bn][1]+bv.y, gg = acc[bn][2]+bv.z, go = acc[bn][3]+bv.w;
        float cc = sigm_(gf)*c[bn] + sigm_(gi)*tanhf(gg);
        float hv = sigm_(go)*tanhf(cc);
        c[bn] = cc;
        P.ys1T[(size_t)t * 131072 + (size_t)col * 1024 + dir * 512 + hg] = bf16b(hv);
        if (s == 511) {
          P.hfin0[(dir * 512 + hg) * 128 + col] = hv;
          P.cfin0[(dir * 512 + hg) * 128 + col] = cc;
        }
      }
      gbar(barMy, s, bid & 63, 4);
    }
  }
  gbar(P.barFull, 0, bid, 8);

  // ================= encoder layer 1 (512 steps) =================
  {
    const short* A = P.AL1 + (size_t)dir * 2048 * 1536;
    const float4 bv = *(const float4*)(P.bpk + (2 + dir) * 2048 + prow4);
    const short* Ap = A + (size_t)rowr * 1536 + q * 8;
    float c[4] = {0.f, 0.f, 0.f, 0.f};
    for (int s = 0; s < 512; ++s) {
      int t  = dir ? 511 - s : s;
      int pr = s & 1, pw = pr ^ 1;
      f32x4 acc[4];
#pragma unroll
      for (int bn = 0; bn < 4; ++bn) acc[bn] = (f32x4){0.f,0.f,0.f,0.f};
      if (s > 0)
        gseg<16, true>(Ap, P.h1T + (size_t)(pr * 2 + dir) * 65536, 512, colr, q, 0, acc);
      gseg<32, false>(Ap, P.ys1T + (size_t)t * 131072, 1024, colr, q, 16, acc);
#pragma unroll
      for (int bn = 0; bn < 4; ++bn) {
        int col = colbase + bn * 16 + r;
        float gi = acc[bn][0]+bv.x, gf = acc[bn][1]+bv.y, gg = acc[bn][2]+bv.z, go = acc[bn][3]+bv.w;
        float cc = sigm_(gf)*c[bn] + sigm_(gi)*tanhf(gg);
        float hv = sigm_(go)*tanhf(cc);
        c[bn] = cc;
        P.h1T[(size_t)(pw * 2 + dir) * 65536 + (size_t)col * 512 + hg] = bf16b(hv);
        if (s == 511) {
          P.hfin1[(dir * 512 + hg) * 128 + col] = hv;
          P.cfin1[(dir * 512 + hg) * 128 + col] = cc;
        }
      }
      gbar(barMy, 512 + s, bid & 63, 4);
    }
  }
  gbar(P.barFull, 1, bid, 8);

  // ================= bidi-state mixing (one shot) =================
  {
    int gid = bid * 4 + w;
    for (int it = 0; it < 8; ++it) {
      int wgl = gid * 8 + it;                 // 4096 tasks
      int sel = wgl >> 11, rem = wgl & 2047, n = rem >> 1, half = rem & 1;
      int b = half * 64 + lane;
      const float* A0 = sel ? P.cfin0 : P.hfin0;
      const float* A2 = sel ? P.cfin1 : P.hfin1;
      const float* Wn = P.wbidi + (size_t)n * 2048;
      float a = P.bbidi[n];
#pragma unroll 8
      for (int k = 0; k < 512; ++k) a = fmaf(A0[k * 128 + b], Wn[k], a);
#pragma unroll 8
      for (int k = 0; k < 512; ++k) a = fmaf(A0[65536 + k * 128 + b], Wn[512 + k], a);
#pragma unroll 8
      for (int k = 0; k < 512; ++k) a = fmaf(A2[k * 128 + b], Wn[1024 + k], a);
#pragma unroll 8
      for (int k = 0; k < 512; ++k) a = fmaf(A2[65536 + k * 128 + b], Wn[1536 + k], a);
      float v = a > 0.f ? a : (__expf(a) - 1.f);
      if (sel == 0)
        P.hdecT[(size_t)(n >> 9) * 65536 + (size_t)b * 512 + (n & 511)] = bf16b(v);
      else
        P.cdec[(size_t)(n >> 9) * 65536 + (size_t)(n & 511) * 128 + b] = v;
    }
  }
  gbar(P.barFull, 2, bid, 8);

  if (bid >= 64) return;   // decoder uses blocks 0..63 only

  // ================= decoder (64 steps) =================
  float cL0[4], cL1[4];
#pragma unroll
  for (int bn = 0; bn < 4; ++bn) {
    int col = colbase + bn * 16 + r;
    cL0[bn] = P.cdec[hg * 128 + col];
    cL1[bn] = P.cdec[65536 + hg * 128 + col];
  }
  const float4 bv0 = *(const float4*)(P.bpk + 4 * 2048 + prow4);
  const float4 bv1 = *(const float4*)(P.bpk + 5 * 2048 + prow4);
  const short* Ap0 = P.AD0 + (size_t)rowr * 640 + q * 8;
  const short* Ap1 = P.AD1 + (size_t)rowr * 1024 + q * 8;

  for (int t = 0; t < 64; ++t) {
    int pr = t & 1, pw = pr ^ 1;
    { // ---- dec cell L0 ----
      f32x4 acc[4];
#pragma unroll
      for (int bn = 0; bn < 4; ++bn) acc[bn] = (f32x4){0.f,0.f,0.f,0.f};
      gseg<16, true>(Ap0, P.hdecT + (size_t)(pr * 2 + 0) * 65536, 512, colr, q, 0, acc);
      gseg<4,  true>(Ap0, P.xdecTb, 128, colr, q, 16, acc);
#pragma unroll
      for (int bn = 0; bn < 4; ++bn) {
        int col = colbase + bn * 16 + r;
        float gi = acc[bn][0]+bv0.x, gf = acc[bn][1]+bv0.y, gg = acc[bn][2]+bv0.z, go = acc[bn][3]+bv0.w;
        float cc = sigm_(gf)*cL0[bn] + sigm_(gi)*tanhf(gg);
        float hv = sigm_(go)*tanhf(cc);
        cL0[bn] = cc;
        P.hdecT[(size_t)(pw * 2 + 0) * 65536 + (size_t)col * 512 + hg] = bf16b(hv);
      }
      gbar(P.barD, t * 3 + 0, bid, 4);
    }
    { // ---- dec cell L1 ----
      f32x4 acc[4];
#pragma unroll
      for (int bn = 0; bn < 4; ++bn) acc[bn] = (f32x4){0.f,0.f,0.f,0.f};
      gseg<16, true>(Ap1, P.hdecT + (size_t)(pw * 2 + 0) * 65536, 512, colr, q, 0, acc);
      gseg<16, true>(Ap1, P.hdecT + (size_t)(pr * 2 + 1) * 65536, 512, colr, q, 16, acc);
#pragma unroll
      for (int bn = 0; bn < 4; ++bn) {
        int col = colbase + bn * 16 + r;
        float gi = acc[bn][0]+bv1.x, gf = acc[bn][1]+bv1.y, gg = acc[bn][2]+bv1.z, go = acc[bn][3]+bv1.w;
        float cc = sigm_(gf)*cL1[bn] + sigm_(gi)*tanhf(gg);
        float hv = sigm_(go)*tanhf(cc);
        cL1[bn] = cc;
        P.hdecT[(size_t)(pw * 2 + 1) * 65536 + (size_t)col * 512 + hg] = bf16b(hv);
        P.hdecF[hg * 128 + col] = hv;
      }
      gbar(P.barD, t * 3 + 1, bid, 4);
    }
    // ---- output projection + feedback ----
    if (bid < 10) {
      int qq = bid >> 1, half = bid & 1;
      int b = half * 64 + lane;
      const float* Wq = P.wout + qq * 512 + w * 128;
      float a = 0.f;
#pragma unroll 8
      for (int k = 0; k < 128; ++k)
        a = fmaf(ld_agcf(P.hdecF + (size_t)(w * 128 + k) * 128 + b), Wq[k], a);
      red[w][lane] = a;
      __syncthreads();
      if (w == 0) {
        float y = red[0][lane] + red[1][lane] + red[2][lane] + red[3][lane] + P.bout[qq];
        P.out[(size_t)b * 320 + t * 5 + qq] = y;
        if (qq == 0 && t + 1 < 64) P.xdecTb[(size_t)b * 128] = bf16b(y);
      }
    } else if (bid == 10 && t + 1 < 64) {
      for (int i = tid; i < 896; i += 256) {
        int b = i / 7, j = i % 7;
        P.xdecTb[(size_t)b * 128 + 1 + j] = bf16b(P.fut[(size_t)b * 448 + (t + 1) * 7 + j]);
      }
    }
    gbar(P.barD, t * 3 + 2, bid, 4);
  }
}

// Pack weights: dst[p][kc] bf16, p=h*4+g; kc<512 <- Whh; 512<=kc<512+XW <- Wih; else 0.
__global__ __launch_bounds__(256) void k_wpack(
    const float* __restrict__ Whh, const float* __restrict__ Wih,
    int XW, int KT, short* __restrict__ dst)
{
  int kc = blockIdx.x * 256 + threadIdx.x;
  int p  = blockIdx.y;
  if (kc >= KT) return;
  int row = (p & 3) * 512 + (p >> 2);
  float v;
  if (kc < 512)           v = Whh[(size_t)row * 512 + kc];
  else if (kc - 512 < XW) v = Wih[(size_t)row * XW + (kc - 512)];
  else                    v = 0.0f;
  dst[(size_t)p * KT + kc] = bf16b(v);
}

__global__ __launch_bounds__(256) void k_bpack(
    const float* b0, const float* b1, const float* b2,
    const float* b3, const float* b4, const float* b5, float* bpk)
{
  int i = blockIdx.x * 256 + threadIdx.x;
  if (i >= 6 * 2048) return;
  int set = i >> 11, p = i & 2047;
  const float* src = set == 0 ? b0 : set == 1 ? b1 : set == 2 ? b2
                   : set == 3 ? b3 : set == 4 ? b4 : b5;
  bpk[i] = src[(p & 3) * 512 + (p >> 2)];
}

// X -> xpT bf16 [t][b][128] (j<8 data, rest 0); block 0 also inits xdecTb.
__global__ __launch_bounds__(256) void k_pre(
    const float* __restrict__ X, const float* __restrict__ fut,
    short* __restrict__ xpT, short* __restrict__ xdecTb)
{
  int t = blockIdx.x, tid = threadIdx.x;
  for (int i = tid; i < 16384; i += 256) {
    int b = i >> 7, j = i & 127;
    float v = (j < 8) ? X[(size_t)b * 4096 + t * 8 + j] : 0.0f;
    xpT[(size_t)t * 16384 + i] = bf16b(v);
  }
  if (t == 0) {
    for (int i = tid; i < 16384; i += 256) {
      int b = i >> 7, j = i & 127;
      float v;
      if (j == 0)     v = X[(size_t)b * 4096 + 511 * 8 + 0];
      else if (j < 8) v = fut[(size_t)b * 448 + (j - 1)];
      else            v = 0.0f;
      xdecTb[i] = bf16b(v);
    }
  }
}

extern "C" void kernel_launch(void* const* d_in, const int* in_sizes, int n_in,
                              void* d_out, int out_size, void* d_ws, size_t ws_size,
                              hipStream_t stream) {
  (void)in_sizes; (void)n_in; (void)out_size; (void)ws_size;
  const float* X      = (const float*)d_in[0];
  const float* fut    = (const float*)d_in[1];
  const float* e_wih0 = (const float*)d_in[4];
  const float* e_whh0 = (const float*)d_in[5];
  const float* e_b0   = (const float*)d_in[6];
  const float* e_wih1 = (const float*)d_in[7];
  const float* e_whh1 = (const float*)d_in[8];
  const float* e_b1   = (const float*)d_in[9];
  const float* d_wih0 = (const float*)d_in[10];
  const float* d_whh0 = (const float*)d_in[11];
  const float* d_b0   = (const float*)d_in[12];
  const float* d_wih1 = (const float*)d_in[13];
  const float* d_whh1 = (const float*)d_in[14];
  const float* d_b1   = (const float*)d_in[15];
  const float* w_bidi = (const float*)d_in[16];
  const float* b_bidi = (const float*)d_in[17];
  const float* w_out  = (const float*)d_in[18];
  const float* b_out  = (const float*)d_in[19];
  float* out = (float*)d_out;

  float* ws = (float*)d_ws;
  // offsets in float units
  short* ys1T   = (short*)(ws + 0);            // 33,554,432 fs
  short* xpT    = (short*)(ws + 33554432);     //  4,194,304 fs
  short* h1T    = (short*)(ws + 37748736);     //    131,072 fs
  short* hdecT  = (short*)(ws + 37879808);     //    131,072 fs
  short* xdecTb = (short*)(ws + 38010880);     //      8,192 fs
  short* ApkL0  = (short*)(ws + 38019072);     //  1,310,720 fs
  short* ApkL1  = (short*)(ws + 39329792);     //  3,145,728 fs
  short* ApkD0  = (short*)(ws + 42475520);     //    655,360 fs
  short* ApkD1  = (short*)(ws + 43130880);     //  1,048,576 fs
  float* bpk    = ws + 44179456;               //     12,288
  float* hfin0  = ws + 44191744;               //    131,072
  float* hfin1  = ws + 44322816;               //    131,072
  float* cfin0  = ws + 44453888;               //    131,072
  float* cfin1  = ws + 44584960;               //    131,072
  float* cdec   = ws + 44716032;               //    131,072
  float* hdecF  = ws + 44847104;               //     65,536
  unsigned* bars = (unsigned*)(ws + 44912640); //     36,864 u32 slots
  // bar layout: barF [1024][16], barB [1024][16], barFull [4][16], barD [200][16]
  unsigned* barF    = bars;
  unsigned* barB    = barF + 1024 * 16;
  unsigned* barFull = barB + 1024 * 16;
  unsigned* barD    = barFull + 4 * 16;

  hipMemsetAsync(bars, 0, (size_t)36864 * 4, stream);
  k_pre<<<512, 256, 0, stream>>>(X, fut, xpT, xdecTb);
  k_wpack<<<dim3(3, 2048), 256, 0, stream>>>(e_whh0, e_wih0, 8, 640, ApkL0);
  k_wpack<<<dim3(3, 2048), 256, 0, stream>>>(e_whh0 + (size_t)2048 * 512,
                                             e_wih0 + 2048 * 8, 8, 640,
                                             ApkL0 + (size_t)2048 * 640);
  k_wpack<<<dim3(6, 2048), 256, 0, stream>>>(e_whh1, e_wih1, 1024, 1536, ApkL1);
  k_wpack<<<dim3(6, 2048), 256, 0, stream>>>(e_whh1 + (size_t)2048 * 512,
                                             e_wih1 + (size_t)2048 * 1024, 1024, 1536,
                                             ApkL1 + (size_t)2048 * 1536);
  k_wpack<<<dim3(3, 2048), 256, 0, stream>>>(d_whh0, d_wih0, 8, 640, ApkD0);
  k_wpack<<<dim3(4, 2048), 256, 0, stream>>>(d_wih1, d_whh1, 512, 1024, ApkD1);
  k_bpack<<<48, 256, 0, stream>>>(e_b0, e_b0 + 2048, e_b1, e_b1 + 2048,
                                  d_b0, d_b1, bpk);

  PK P;
  P.AL0 = ApkL0; P.AL1 = ApkL1; P.AD0 = ApkD0; P.AD1 = ApkD1;
  P.bpk = bpk;
  P.ys1T = ys1T; P.xpT = xpT; P.h1T = h1T; P.hdecT = hdecT; P.xdecTb = xdecTb;
  P.hfin0 = hfin0; P.hfin1 = hfin1; P.cfin0 = cfin0; P.cfin1 = cfin1;
  P.cdec = cdec; P.hdecF = hdecF;
  P.wbidi = w_bidi; P.bbidi = b_bidi; P.wout = w_out; P.bout = b_out; P.fut = fut;
  P.out = out;
  P.barF = barF; P.barB = barB; P.barFull = barFull; P.barD = barD;

  k_perst<<<128, 256, 0, stream>>>(P);
}

// Round 8
// 39611.337 us; speedup vs baseline: 1.0690x; 1.0690x over previous
//
#include <hip/hip_runtime.h>
#include <hip/hip_bf16.h>
#include <cstddef>
#include <cstdint>

// ---------------------------------------------------------------------------
// RecurrentEncoderDecoder (B=128, T=512, H=512, HOR=64, M=1, Q=5, DFF=7)
// Round 8: kill the per-barrier buffer_wbl2 (rounds 6/7: 35 us/step, 618 MB
// WRITE_SIZE, 97% idle — agent AND system release both must flush L2 on
// multi-XCD gfx950). Strategy: never dirty L2 with shared data. All
// cross-block h-state / feedback writes use relaxed agent-scope atomic
// stores (sc1 write-through -> shared L3); per-step barriers are then pure
// relaxed fetch_add + relaxed poll (no fence, no wbl2). Reads of mutable
// state use sc1 loads (L3-fresh). Only the 3 phase barriers keep RELEASE.
// Everything else identical to passing round 7.
// ---------------------------------------------------------------------------

typedef __attribute__((ext_vector_type(8))) short short8;
typedef __attribute__((ext_vector_type(4))) float f32x4;

__device__ __forceinline__ float sigm_(float x){ return 1.0f/(1.0f+__expf(-x)); }

__device__ __forceinline__ short bf16b(float x){
  __hip_bfloat16 h = __float2bfloat16(x);
  union { __hip_bfloat16 h; short s; } u; u.h = h; return u.s;
}

// 16B load, agent-scope relaxed (sc1: bypass local L2, served L3-fresh).
__device__ __forceinline__ short8 ld_agc8(const short* p){
  union { unsigned long long u[2]; short8 s; } cv;
  cv.u[0] = __hip_atomic_load((const unsigned long long*)p,     __ATOMIC_RELAXED, __HIP_MEMORY_SCOPE_AGENT);
  cv.u[1] = __hip_atomic_load(((const unsigned long long*)p)+1, __ATOMIC_RELAXED, __HIP_MEMORY_SCOPE_AGENT);
  return cv.s;
}
__device__ __forceinline__ float ld_agcf(const float* p){
  unsigned u = __hip_atomic_load((const unsigned*)p, __ATOMIC_RELAXED, __HIP_MEMORY_SCOPE_AGENT);
  union { unsigned u; float f; } c; c.u = u; return c.f;
}
// Write-through stores (sc1): update shared L3, leave no dirty L2 line.
__device__ __forceinline__ void st_agh(short* p, short v){
  __hip_atomic_store(p, v, __ATOMIC_RELAXED, __HIP_MEMORY_SCOPE_AGENT);
}
__device__ __forceinline__ void st_agf(float* p, float v){
  __hip_atomic_store(p, v, __ATOMIC_RELAXED, __HIP_MEMORY_SCOPE_AGENT);
}

// One B-segment of the gate GEMM. Ap already includes row*KT + q*8.
template<int KN, bool SYS>
__device__ __forceinline__ void gseg(const short* __restrict__ Ap,
                                     const short* __restrict__ S, int ld,
                                     int colr, int q, int a_k32_off,
                                     f32x4 (&acc)[4])
{
#pragma unroll 4
  for (int k32 = 0; k32 < KN; ++k32) {
    short8 a = *(const short8*)(Ap + (size_t)(a_k32_off + k32) * 32);
#pragma unroll
    for (int bn = 0; bn < 4; ++bn) {
      const short* bp = S + (size_t)(colr + bn * 16) * ld + k32 * 32 + q * 8;
      short8 b;
      if constexpr (SYS) b = ld_agc8(bp); else b = *(const short8*)bp;
      acc[bn] = __builtin_amdgcn_mfma_f32_16x16x32_bf16(a, b, acc[bn], 0, 0, 0);
    }
  }
}

// FAST per-step tree barrier: no release, no wbl2. Data was written via sc1
// write-through stores; the pre-barrier vmcnt drain (each wave) makes them
// L3-visible before the relaxed arrive.
__device__ __forceinline__ void gbar_rlx(unsigned* base, int seq, int gbid, int nleaf)
{
  asm volatile("s_waitcnt vmcnt(0)" ::: "memory");
  __syncthreads();
  if (threadIdx.x == 0) {
    unsigned* bb = base + (size_t)seq * 16;
    unsigned prev = __hip_atomic_fetch_add(bb + (gbid >> 4), 1u, __ATOMIC_RELAXED, __HIP_MEMORY_SCOPE_AGENT);
    if (prev == 15u)
      __hip_atomic_fetch_add(bb + 15, 1u, __ATOMIC_RELAXED, __HIP_MEMORY_SCOPE_AGENT);
    while (__hip_atomic_load(bb + 15, __ATOMIC_RELAXED, __HIP_MEMORY_SCOPE_AGENT) < (unsigned)nleaf)
      __builtin_amdgcn_s_sleep(1);
  }
  __syncthreads();
}

// Phase barrier: RELEASE arrive (wbl2) to flush the phase's plain writes.
__device__ __forceinline__ void gbar_rel(unsigned* base, int seq, int gbid, int nleaf)
{
  __syncthreads();
  if (threadIdx.x == 0) {
    unsigned* bb = base + (size_t)seq * 16;
    unsigned prev = __hip_atomic_fetch_add(bb + (gbid >> 4), 1u, __ATOMIC_RELEASE, __HIP_MEMORY_SCOPE_AGENT);
    if (prev == 15u)
      __hip_atomic_fetch_add(bb + 15, 1u, __ATOMIC_RELEASE, __HIP_MEMORY_SCOPE_AGENT);
    while (__hip_atomic_load(bb + 15, __ATOMIC_RELAXED, __HIP_MEMORY_SCOPE_AGENT) < (unsigned)nleaf)
      __builtin_amdgcn_s_sleep(1);
  }
  __syncthreads();
}

struct PK {
  const short *AL0, *AL1, *AD0, *AD1;   // packed bf16 weights
  const float *bpk;                      // packed biases [6][2048]
  short *ys1T;        // [512][128][1024] bf16 (L0 h record, fwd k<512 / bwd k>=512)
  short *xpT;         // [512][128][128] bf16, x padded
  short *h1T;         // [par2*dir2][128][512] bf16
  short *hdecT;       // [par2*lay2][128][512] bf16
  short *xdecTb;      // [128][128] bf16
  float *hfin0, *hfin1, *cfin0, *cfin1;  // [2][512][128] f32
  float *cdec;        // [2][512][128]
  float *hdecF;       // [512][128]
  const float *wbidi, *bbidi, *wout, *bout, *fut;
  float *out;
  unsigned *barF, *barB, *barFull, *barD;
};

__global__ __launch_bounds__(256) void k_perst(PK P)
{
  __shared__ float red[4][64];
  const int bid  = blockIdx.x;
  const int tid  = threadIdx.x;
  const int lane = tid & 63;
  const int w    = tid >> 6;
  const int r    = lane & 15, q = lane >> 4;
  const int dir  = bid >> 6;
  const int task = (bid & 63) * 4 + w;
  const int rt   = task >> 1, ct = task & 1;
  const int colbase = ct * 64;
  const int colr = colbase + r;
  const int rowr = rt * 16 + r;
  const int hg   = rt * 4 + q;          // global h row this lane owns
  const int prow4 = rt * 16 + q * 4;    // packed-row base for bias float4
  unsigned* barMy = dir ? P.barB : P.barF;

  // ================= encoder layer 0 (512 steps) =================
  {
    const short* A = P.AL0 + (size_t)dir * 2048 * 640;
    const float4 bv = *(const float4*)(P.bpk + dir * 2048 + prow4);
    const short* Ap = A + (size_t)rowr * 640 + q * 8;
    float c[4] = {0.f, 0.f, 0.f, 0.f};
    for (int s = 0; s < 512; ++s) {
      int t  = dir ? 511 - s : s;
      int tp = dir ? 512 - s : s - 1;     // prev-h time slab (unique addr/step)
      f32x4 acc[4];
#pragma unroll
      for (int bn = 0; bn < 4; ++bn) acc[bn] = (f32x4){0.f,0.f,0.f,0.f};
      if (s > 0)
        gseg<16, false>(Ap, P.ys1T + (size_t)tp * 131072 + dir * 512, 1024, colr, q, 0, acc);
      gseg<4, false>(Ap, P.xpT + (size_t)t * 16384, 128, colr, q, 16, acc);
#pragma unroll
      for (int bn = 0; bn < 4; ++bn) {
        int col = colbase + bn * 16 + r;
        float gi = acc[bn][0]+bv.x, gf = acc[bn][1]+bv.y, gg = acc[bn][2]+bv.z, go = acc[bn][3]+bv.w;
        float cc = sigm_(gf)*c[bn] + sigm_(gi)*tanhf(gg);
        float hv = sigm_(go)*tanhf(cc);
        c[bn] = cc;
        st_agh(&P.ys1T[(size_t)t * 131072 + (size_t)col * 1024 + dir * 512 + hg], bf16b(hv));
        if (s == 511) {
          P.hfin0[(dir * 512 + hg) * 128 + col] = hv;
          P.cfin0[(dir * 512 + hg) * 128 + col] = cc;
        }
      }
      gbar_rlx(barMy, s, bid & 63, 4);
    }
  }
  gbar_rel(P.barFull, 0, bid, 8);

  // ================= encoder layer 1 (512 steps) =================
  {
    const short* A = P.AL1 + (size_t)dir * 2048 * 1536;
    const float4 bv = *(const float4*)(P.bpk + (2 + dir) * 2048 + prow4);
    const short* Ap = A + (size_t)rowr * 1536 + q * 8;
    float c[4] = {0.f, 0.f, 0.f, 0.f};
    for (int s = 0; s < 512; ++s) {
      int t  = dir ? 511 - s : s;
      int pr = s & 1, pw = pr ^ 1;
      f32x4 acc[4];
#pragma unroll
      for (int bn = 0; bn < 4; ++bn) acc[bn] = (f32x4){0.f,0.f,0.f,0.f};
      if (s > 0)
        gseg<16, true>(Ap, P.h1T + (size_t)(pr * 2 + dir) * 65536, 512, colr, q, 0, acc);
      gseg<32, false>(Ap, P.ys1T + (size_t)t * 131072, 1024, colr, q, 16, acc);
#pragma unroll
      for (int bn = 0; bn < 4; ++bn) {
        int col = colbase + bn * 16 + r;
        float gi = acc[bn][0]+bv.x, gf = acc[bn][1]+bv.y, gg = acc[bn][2]+bv.z, go = acc[bn][3]+bv.w;
        float cc = sigm_(gf)*c[bn] + sigm_(gi)*tanhf(gg);
        float hv = sigm_(go)*tanhf(cc);
        c[bn] = cc;
        st_agh(&P.h1T[(size_t)(pw * 2 + dir) * 65536 + (size_t)col * 512 + hg], bf16b(hv));
        if (s == 511) {
          P.hfin1[(dir * 512 + hg) * 128 + col] = hv;
          P.cfin1[(dir * 512 + hg) * 128 + col] = cc;
        }
      }
      gbar_rlx(barMy, 512 + s, bid & 63, 4);
    }
  }
  gbar_rel(P.barFull, 1, bid, 8);

  // ================= bidi-state mixing (one shot) =================
  {
    int gid = bid * 4 + w;
    for (int it = 0; it < 8; ++it) {
      int wgl = gid * 8 + it;                 // 4096 tasks
      int sel = wgl >> 11, rem = wgl & 2047, n = rem >> 1, half = rem & 1;
      int b = half * 64 + lane;
      const float* A0 = sel ? P.cfin0 : P.hfin0;
      const float* A2 = sel ? P.cfin1 : P.hfin1;
      const float* Wn = P.wbidi + (size_t)n * 2048;
      float a = P.bbidi[n];
#pragma unroll 8
      for (int k = 0; k < 512; ++k) a = fmaf(A0[k * 128 + b], Wn[k], a);
#pragma unroll 8
      for (int k = 0; k < 512; ++k) a = fmaf(A0[65536 + k * 128 + b], Wn[512 + k], a);
#pragma unroll 8
      for (int k = 0; k < 512; ++k) a = fmaf(A2[k * 128 + b], Wn[1024 + k], a);
#pragma unroll 8
      for (int k = 0; k < 512; ++k) a = fmaf(A2[65536 + k * 128 + b], Wn[1536 + k], a);
      float v = a > 0.f ? a : (__expf(a) - 1.f);
      if (sel == 0)
        P.hdecT[(size_t)(n >> 9) * 65536 + (size_t)b * 512 + (n & 511)] = bf16b(v);
      else
        P.cdec[(size_t)(n >> 9) * 65536 + (size_t)(n & 511) * 128 + b] = v;
    }
  }
  gbar_rel(P.barFull, 2, bid, 8);

  if (bid >= 64) return;   // decoder uses blocks 0..63 only

  // ================= decoder (64 steps) =================
  float cL0[4], cL1[4];
#pragma unroll
  for (int bn = 0; bn < 4; ++bn) {
    int col = colbase + bn * 16 + r;
    cL0[bn] = P.cdec[hg * 128 + col];
    cL1[bn] = P.cdec[65536 + hg * 128 + col];
  }
  const float4 bv0 = *(const float4*)(P.bpk + 4 * 2048 + prow4);
  const float4 bv1 = *(const float4*)(P.bpk + 5 * 2048 + prow4);
  const short* Ap0 = P.AD0 + (size_t)rowr * 640 + q * 8;
  const short* Ap1 = P.AD1 + (size_t)rowr * 1024 + q * 8;

  for (int t = 0; t < 64; ++t) {
    int pr = t & 1, pw = pr ^ 1;
    { // ---- dec cell L0 ----
      f32x4 acc[4];
#pragma unroll
      for (int bn = 0; bn < 4; ++bn) acc[bn] = (f32x4){0.f,0.f,0.f,0.f};
      gseg<16, true>(Ap0, P.hdecT + (size_t)(pr * 2 + 0) * 65536, 512, colr, q, 0, acc);
      gseg<4,  true>(Ap0, P.xdecTb, 128, colr, q, 16, acc);
#pragma unroll
      for (int bn = 0; bn < 4; ++bn) {
        int col = colbase + bn * 16 + r;
        float gi = acc[bn][0]+bv0.x, gf = acc[bn][1]+bv0.y, gg = acc[bn][2]+bv0.z, go = acc[bn][3]+bv0.w;
        float cc = sigm_(gf)*cL0[bn] + sigm_(gi)*tanhf(gg);
        float hv = sigm_(go)*tanhf(cc);
        cL0[bn] = cc;
        st_agh(&P.hdecT[(size_t)(pw * 2 + 0) * 65536 + (size_t)col * 512 + hg], bf16b(hv));
      }
      gbar_rlx(P.barD, t * 3 + 0, bid, 4);
    }
    { // ---- dec cell L1 ----
      f32x4 acc[4];
#pragma unroll
      for (int bn = 0; bn < 4; ++bn) acc[bn] = (f32x4){0.f,0.f,0.f,0.f};
      gseg<16, true>(Ap1, P.hdecT + (size_t)(pw * 2 + 0) * 65536, 512, colr, q, 0, acc);
      gseg<16, true>(Ap1, P.hdecT + (size_t)(pr * 2 + 1) * 65536, 512, colr, q, 16, acc);
#pragma unroll
      for (int bn = 0; bn < 4; ++bn) {
        int col = colbase + bn * 16 + r;
        float gi = acc[bn][0]+bv1.x, gf = acc[bn][1]+bv1.y, gg = acc[bn][2]+bv1.z, go = acc[bn][3]+bv1.w;
        float cc = sigm_(gf)*cL1[bn] + sigm_(gi)*tanhf(gg);
        float hv = sigm_(go)*tanhf(cc);
        cL1[bn] = cc;
        st_agh(&P.hdecT[(size_t)(pw * 2 + 1) * 65536 + (size_t)col * 512 + hg], bf16b(hv));
        st_agf(&P.hdecF[hg * 128 + col], hv);
      }
      gbar_rlx(P.barD, t * 3 + 1, bid, 4);
    }
    // ---- output projection + feedback ----
    if (bid < 10) {
      int qq = bid >> 1, half = bid & 1;
      int b = half * 64 + lane;
      const float* Wq = P.wout + qq * 512 + w * 128;
      float a = 0.f;
#pragma unroll 8
      for (int k = 0; k < 128; ++k)
        a = fmaf(ld_agcf(P.hdecF + (size_t)(w * 128 + k) * 128 + b), Wq[k], a);
      red[w][lane] = a;
      __syncthreads();
      if (w == 0) {
        float y = red[0][lane] + red[1][lane] + red[2][lane] + red[3][lane] + P.bout[qq];
        P.out[(size_t)b * 320 + t * 5 + qq] = y;
        if (qq == 0 && t + 1 < 64) st_agh(&P.xdecTb[(size_t)b * 128], bf16b(y));
      }
    } else if (bid == 10 && t + 1 < 64) {
      for (int i = tid; i < 896; i += 256) {
        int b = i / 7, j = i % 7;
        st_agh(&P.xdecTb[(size_t)b * 128 + 1 + j], bf16b(P.fut[(size_t)b * 448 + (t + 1) * 7 + j]));
      }
    }
    gbar_rlx(P.barD, t * 3 + 2, bid, 4);
  }
}

// Pack weights: dst[p][kc] bf16, p=h*4+g; kc<512 <- Whh; 512<=kc<512+XW <- Wih; else 0.
__global__ __launch_bounds__(256) void k_wpack(
    const float* __restrict__ Whh, const float* __restrict__ Wih,
    int XW, int KT, short* __restrict__ dst)
{
  int kc = blockIdx.x * 256 + threadIdx.x;
  int p  = blockIdx.y;
  if (kc >= KT) return;
  int row = (p & 3) * 512 + (p >> 2);
  float v;
  if (kc < 512)           v = Whh[(size_t)row * 512 + kc];
  else if (kc - 512 < XW) v = Wih[(size_t)row * XW + (kc - 512)];
  else                    v = 0.0f;
  dst[(size_t)p * KT + kc] = bf16b(v);
}

__global__ __launch_bounds__(256) void k_bpack(
    const float* b0, const float* b1, const float* b2,
    const float* b3, const float* b4, const float* b5, float* bpk)
{
  int i = blockIdx.x * 256 + threadIdx.x;
  if (i >= 6 * 2048) return;
  int set = i >> 11, p = i & 2047;
  const float* src = set == 0 ? b0 : set == 1 ? b1 : set == 2 ? b2
                   : set == 3 ? b3 : set == 4 ? b4 : b5;
  bpk[i] = src[(p & 3) * 512 + (p >> 2)];
}

// X -> xpT bf16 [t][b][128] (j<8 data, rest 0); block 0 also inits xdecTb.
__global__ __launch_bounds__(256) void k_pre(
    const float* __restrict__ X, const float* __restrict__ fut,
    short* __restrict__ xpT, short* __restrict__ xdecTb)
{
  int t = blockIdx.x, tid = threadIdx.x;
  for (int i = tid; i < 16384; i += 256) {
    int b = i >> 7, j = i & 127;
    float v = (j < 8) ? X[(size_t)b * 4096 + t * 8 + j] : 0.0f;
    xpT[(size_t)t * 16384 + i] = bf16b(v);
  }
  if (t == 0) {
    for (int i = tid; i < 16384; i += 256) {
      int b = i >> 7, j = i & 127;
      float v;
      if (j == 0)     v = X[(size_t)b * 4096 + 511 * 8 + 0];
      else if (j < 8) v = fut[(size_t)b * 448 + (j - 1)];
      else            v = 0.0f;
      xdecTb[i] = bf16b(v);
    }
  }
}

extern "C" void kernel_launch(void* const* d_in, const int* in_sizes, int n_in,
                              void* d_out, int out_size, void* d_ws, size_t ws_size,
                              hipStream_t stream) {
  (void)in_sizes; (void)n_in; (void)out_size; (void)ws_size;
  const float* X      = (const float*)d_in[0];
  const float* fut    = (const float*)d_in[1];
  const float* e_wih0 = (const float*)d_in[4];
  const float* e_whh0 = (const float*)d_in[5];
  const float* e_b0   = (const float*)d_in[6];
  const float* e_wih1 = (const float*)d_in[7];
  const float* e_whh1 = (const float*)d_in[8];
  const float* e_b1   = (const float*)d_in[9];
  const float* d_wih0 = (const float*)d_in[10];
  const float* d_whh0 = (const float*)d_in[11];
  const float* d_b0   = (const float*)d_in[12];
  const float* d_wih1 = (const float*)d_in[13];
  const float* d_whh1 = (const float*)d_in[14];
  const float* d_b1   = (const float*)d_in[15];
  const float* w_bidi = (const float*)d_in[16];
  const float* b_bidi = (const float*)d_in[17];
  const float* w_out  = (const float*)d_in[18];
  const float* b_out  = (const float*)d_in[19];
  float* out = (float*)d_out;

  float* ws = (float*)d_ws;
  // offsets in float units
  short* ys1T   = (short*)(ws + 0);            // 33,554,432 fs
  short* xpT    = (short*)(ws + 33554432);     //  4,194,304 fs
  short* h1T    = (short*)(ws + 37748736);     //    131,072 fs
  short* hdecT  = (short*)(ws + 37879808);     //    131,072 fs
  short* xdecTb = (short*)(ws + 38010880);     //      8,192 fs
  short* ApkL0  = (short*)(ws + 38019072);     //  1,310,720 fs
  short* ApkL1  = (short*)(ws + 39329792);     //  3,145,728 fs
  short* ApkD0  = (short*)(ws + 42475520);     //    655,360 fs
  short* ApkD1  = (short*)(ws + 43130880);     //  1,048,576 fs
  float* bpk    = ws + 44179456;               //     12,288
  float* hfin0  = ws + 44191744;               //    131,072
  float* hfin1  = ws + 44322816;               //    131,072
  float* cfin0  = ws + 44453888;               //    131,072
  float* cfin1  = ws + 44584960;               //    131,072
  float* cdec   = ws + 44716032;               //    131,072
  float* hdecF  = ws + 44847104;               //     65,536
  unsigned* bars = (unsigned*)(ws + 44912640); //     36,864 u32 slots
  // bar layout: barF [1024][16], barB [1024][16], barFull [4][16], barD [200][16]
  unsigned* barF    = bars;
  unsigned* barB    = barF + 1024 * 16;
  unsigned* barFull = barB + 1024 * 16;
  unsigned* barD    = barFull + 4 * 16;

  hipMemsetAsync(bars, 0, (size_t)36864 * 4, stream);
  k_pre<<<512, 256, 0, stream>>>(X, fut, xpT, xdecTb);
  k_wpack<<<dim3(3, 2048), 256, 0, stream>>>(e_whh0, e_wih0, 8, 640, ApkL0);
  k_wpack<<<dim3(3, 2048), 256, 0, stream>>>(e_whh0 + (size_t)2048 * 512,
                                             e_wih0 + 2048 * 8, 8, 640,
                                             ApkL0 + (size_t)2048 * 640);
  k_wpack<<<dim3(6, 2048), 256, 0, stream>>>(e_whh1, e_wih1, 1024, 1536, ApkL1);
  k_wpack<<<dim3(6, 2048), 256, 0, stream>>>(e_whh1 + (size_t)2048 * 512,
                                             e_wih1 + (size_t)2048 * 1024, 1024, 1536,
                                             ApkL1 + (size_t)2048 * 1536);
  k_wpack<<<dim3(3, 2048), 256, 0, stream>>>(d_whh0, d_wih0, 8, 640, ApkD0);
  k_wpack<<<dim3(4, 2048), 256, 0, stream>>>(d_wih1, d_whh1, 512, 1024, ApkD1);
  k_bpack<<<48, 256, 0, stream>>>(e_b0, e_b0 + 2048, e_b1, e_b1 + 2048,
                                  d_b0, d_b1, bpk);

  PK P;
  P.AL0 = ApkL0; P.AL1 = ApkL1; P.AD0 = ApkD0; P.AD1 = ApkD1;
  P.bpk = bpk;
  P.ys1T = ys1T; P.xpT = xpT; P.h1T = h1T; P.hdecT = hdecT; P.xdecTb = xdecTb;
  P.hfin0 = hfin0; P.hfin1 = hfin1; P.cfin0 = cfin0; P.cfin1 = cfin1;
  P.cdec = cdec; P.hdecF = hdecF;
  P.wbidi = w_bidi; P.bbidi = b_bidi; P.wout = w_out; P.bout = b_out; P.fut = fut;
  P.out = out;
  P.barF = barF; P.barB = barB; P.barFull = barFull; P.barD = barD;

  k_perst<<<128, 256, 0, stream>>>(P);
}